// Round 6
// baseline (819.113 us; speedup 1.0000x reference)
//
#include <hip/hip_runtime.h>

// GCN 2-layer, N=100000, E=3200000, 13 -> 32 -> 16.
// v5: single-level bucket sort (dst>>7, 782 buckets, fixed-capacity regions,
// NO prefix scan / NO CSR), then per-bucket gather + LDS-atomic accumulation.
// binB, scanTop, off/srcs eliminated: 2 edge-walks instead of 4 + aggregation.

constexpr int N_NODES = 100000;
constexpr int N_EDGES = 3200000;
constexpr int IN_CH  = 13;
constexpr int HID_CH = 32;
constexpr int LAT_CH = 16;

constexpr int NPB  = 128;                    // nodes per bucket (dst>>7)
constexpr int NBKT = (N_NODES + NPB - 1) / NPB;  // 782
constexpr int BCAP = 4608;                   // mean 4096, sd ~64 -> 8 sigma
constexpr int TILE = 16384;                  // edges per binA block

__global__ __launch_bounds__(256) void k_zero_bcur(int* __restrict__ bcur) {
    int i = blockIdx.x * 256 + threadIdx.x;
    if (i < NBKT) bcur[i] = 0;
}

// bin edges into fixed-capacity bucket regions; word = (dst&127)<<17 | src
__global__ __launch_bounds__(1024) void k_binA(const int* __restrict__ src,
                                               const int* __restrict__ dst,
                                               int* __restrict__ bcur,
                                               int* __restrict__ buckets) {
    __shared__ int h[NBKT], st[NBKT], cur[NBKT];
    int tid = threadIdx.x;
    for (int i = tid; i < NBKT; i += 1024) h[i] = 0;
    __syncthreads();
    int e0 = blockIdx.x * TILE;
    for (int i = tid; i < TILE; i += 1024) {
        int e = e0 + i;
        if (e < N_EDGES) atomicAdd(&h[dst[e] >> 7], 1);
    }
    __syncthreads();
    for (int i = tid; i < NBKT; i += 1024) {
        int c = h[i];
        st[i] = c > 0 ? atomicAdd(&bcur[i], c) : 0;
        cur[i] = 0;
    }
    __syncthreads();
    for (int i = tid; i < TILE; i += 1024) {
        int e = e0 + i;
        if (e < N_EDGES) {
            int d = dst[e];
            int b = d >> 7;
            int r = atomicAdd(&cur[b], 1);
            buckets[b * BCAP + st[b] + r] = src[e] | ((d & 127) << 17);
        }
    }
}

// per-bucket degree histogram -> dis[node] = rsqrt(deg+1)
__global__ __launch_bounds__(256) void k_degdis(const int* __restrict__ bcur,
                                                const int* __restrict__ buckets,
                                                float* __restrict__ dis) {
    __shared__ int h[NPB];
    int b = blockIdx.x, tid = threadIdx.x;
    if (tid < NPB) h[tid] = 0;
    __syncthreads();
    int cnt = bcur[b];
    if (cnt > BCAP) cnt = BCAP;
    const int* bw = buckets + b * BCAP;
    for (int i = tid; i < cnt; i += 256) atomicAdd(&h[bw[i] >> 17], 1);
    __syncthreads();
    if (tid < NPB) {
        int node = b * NPB + tid;
        if (node < N_NODES) dis[node] = rsqrtf((float)(h[tid] + 1));  // +1 self-loop
    }
}

// xn[i*16+c] = (c<13 ? x[i*13+c] : 0) * dis[i]
__global__ __launch_bounds__(256) void k_xn(const float* __restrict__ x,
                                            const float* __restrict__ dis,
                                            float* __restrict__ xn) {
    int idx = blockIdx.x * 256 + threadIdx.x;
    if (idx >= N_NODES * 16) return;
    int node = idx >> 4, c = idx & 15;
    xn[idx] = (c < IN_CH) ? x[node * IN_CH + c] * dis[node] : 0.f;
}

// one block per bucket: gather vin rows for the bucket's edges (dual-window,
// 2 float4/lane in flight, word prefetch) and accumulate into a 128x16 LDS
// tile (stride 17 floats to spread banks) with LDS atomics. Epilogue adds the
// self-loop row, scales by dis, adds bias, writes coalesced float4.
__global__ __launch_bounds__(512) void k_aggB(const int* __restrict__ bcur,
                                              const int* __restrict__ buckets,
                                              const float* __restrict__ dis,
                                              const float* __restrict__ vin,
                                              const float* __restrict__ bias,  // may be null
                                              float* __restrict__ outv) {
    __shared__ float acc[NPB * 17];
    int b = blockIdx.x, tid = threadIdx.x;
    for (int i = tid; i < NPB * 17; i += 512) acc[i] = 0.f;
    __syncthreads();
    int cnt = bcur[b];
    if (cnt > BCAP) cnt = BCAP;
    const int* bw = buckets + b * BCAP;
    int lane = tid & 63;
    int wid  = tid >> 6;       // wave 0..7
    int q    = lane & 3;       // channel quad
    int esub = lane >> 2;      // word slot 0..15 (and +16 second window)

    int k1 = wid * 32 + esub;
    int w1 = (k1 < cnt)      ? bw[k1]      : -1;
    int w2 = (k1 + 16 < cnt) ? bw[k1 + 16] : -1;
    for (int kb = wid * 32; kb < cnt; kb += 8 * 32) {
        int kn = kb + 8 * 32 + esub;
        int wn1 = (kn < cnt)      ? bw[kn]      : -1;
        int wn2 = (kn + 16 < cnt) ? bw[kn + 16] : -1;
        float4 v1, v2;
        v1.x = v1.y = v1.z = v1.w = 0.f;
        v2.x = v2.y = v2.z = v2.w = 0.f;
        int d1 = 0, d2 = 0;
        if (w1 >= 0) { d1 = w1 >> 17; v1 = *((const float4*)(vin + (size_t)(w1 & 131071) * 16) + q); }
        if (w2 >= 0) { d2 = w2 >> 17; v2 = *((const float4*)(vin + (size_t)(w2 & 131071) * 16) + q); }
        if (w1 >= 0) {
            float* a = &acc[d1 * 17 + q * 4];
            atomicAdd(a + 0, v1.x); atomicAdd(a + 1, v1.y);
            atomicAdd(a + 2, v1.z); atomicAdd(a + 3, v1.w);
        }
        if (w2 >= 0) {
            float* a = &acc[d2 * 17 + q * 4];
            atomicAdd(a + 0, v2.x); atomicAdd(a + 1, v2.y);
            atomicAdd(a + 2, v2.z); atomicAdd(a + 3, v2.w);
        }
        w1 = wn1; w2 = wn2;
    }
    __syncthreads();
    // epilogue: 512 threads = 128 nodes x 4 quads
    int node = tid >> 2, qq = tid & 3;
    int gnode = b * NPB + node;
    if (gnode < N_NODES) {
        const float* a = &acc[node * 17 + qq * 4];
        const float4 self = *((const float4*)(vin + (size_t)gnode * 16) + qq);
        float dsc = dis[gnode];
        float4 r;
        r.x = dsc * (a[0] + self.x);
        r.y = dsc * (a[1] + self.y);
        r.z = dsc * (a[2] + self.z);
        r.w = dsc * (a[3] + self.w);
        if (bias) {
            const float4 bq = ((const float4*)bias)[qq];
            r.x += bq.x; r.y += bq.y; r.z += bq.z; r.w += bq.w;
        }
        *((float4*)(outv + (size_t)gnode * 16) + qq) = r;
    }
}

// fused: hwn = (relu(s1 @ W1 + b1) @ W2) * dis   (per node, through LDS)
__global__ __launch_bounds__(256) void k_gemm12(const float* __restrict__ s1,
                                                const float* __restrict__ W1,
                                                const float* __restrict__ b1,
                                                const float* __restrict__ W2,
                                                const float* __restrict__ dis,
                                                float* __restrict__ hwn) {
    __shared__ float sW1[IN_CH * HID_CH];
    __shared__ float sW2[HID_CH * LAT_CH];
    __shared__ float sr[8][HID_CH + 1];
    int tid = threadIdx.x;
    for (int i = tid; i < IN_CH * HID_CH; i += 256) sW1[i] = W1[i];
    for (int i = tid; i < HID_CH * LAT_CH; i += 256) sW2[i] = W2[i];
    __syncthreads();
    int nl = tid >> 5, c1 = tid & 31;
    int node = blockIdx.x * 8 + nl;
    float r = 0.f;
    if (node < N_NODES) {
        float acc = b1[c1];
#pragma unroll
        for (int k = 0; k < IN_CH; ++k)
            acc += s1[node * 16 + k] * sW1[k * HID_CH + c1];
        r = acc > 0.f ? acc : 0.f;   // ReLU
    }
    sr[nl][c1] = r;
    __syncthreads();
    if (tid < 128) {
        int nl2 = tid >> 4, c2 = tid & 15;
        int node2 = blockIdx.x * 8 + nl2;
        if (node2 < N_NODES) {
            float acc = 0.f;
#pragma unroll
            for (int k = 0; k < HID_CH; ++k)
                acc += sr[nl2][k] * sW2[k * LAT_CH + c2];
            hwn[node2 * 16 + c2] = acc * dis[node2];
        }
    }
}

extern "C" void kernel_launch(void* const* d_in, const int* in_sizes, int n_in,
                              void* d_out, int out_size, void* d_ws, size_t ws_size,
                              hipStream_t stream) {
    const float* x  = (const float*)d_in[0];
    const int*   ei = (const int*)d_in[1];
    const float* W1 = (const float*)d_in[2];
    const float* b1 = (const float*)d_in[3];
    const float* W2 = (const float*)d_in[4];
    const float* b2 = (const float*)d_in[5];
    float* out = (float*)d_out;

    const int* src = ei;
    const int* dst = ei + N_EDGES;

    // ws layout (bytes):
    //   bcur[782] @ 0 (pad 4096)
    //   dis[N]    @ 4096
    //   buckets   @ 404096   (782*4608*4 = 14,413,824)
    //   xn        @ 14817920 (6.4MB)
    //   s1        @ 21217920 (6.4MB)
    //   hwn aliases xn (xn dead after first aggB)
    char* ws = (char*)d_ws;
    int*   bcur    = (int*)(ws);
    float* dis     = (float*)(ws + 4096);
    int*   buckets = (int*)(ws + 404096);
    float* xn      = (float*)(ws + 14817920);
    float* s1      = (float*)(ws + 21217920);
    float* hwn     = xn;

    const int NB_A  = (N_EDGES + TILE - 1) / TILE;      // 196
    const int NB_Z  = (NBKT + 255) / 256;               // 4
    const int NB_N16= (N_NODES * 16 + 255) / 256;
    const int NB_G  = (N_NODES + 7) / 8;

    k_zero_bcur<<<NB_Z, 256, 0, stream>>>(bcur);
    k_binA     <<<NB_A, 1024, 0, stream>>>(src, dst, bcur, buckets);
    k_degdis   <<<NBKT, 256, 0, stream>>>(bcur, buckets, dis);
    k_xn       <<<NB_N16, 256, 0, stream>>>(x, dis, xn);
    k_aggB     <<<NBKT, 512, 0, stream>>>(bcur, buckets, dis, xn, nullptr, s1);
    k_gemm12   <<<NB_G,  256, 0, stream>>>(s1, W1, b1, W2, dis, hwn);
    k_aggB     <<<NBKT, 512, 0, stream>>>(bcur, buckets, dis, hwn, b2, out);
}

// Round 7
// 230.388 us; speedup vs baseline: 3.5554x; 3.5554x over previous
//
#include <hip/hip_runtime.h>

// GCN 2-layer, N=100000, E=3200000, 13 -> 32 -> 16.
// v6 = round-3 structure (two-level counting sort + CSR, best 239.7us) with
// k_agg v3: 4 nodes per wave (16 lanes/node: 4 edge slots x 4 quads, dual
// window) so each latency chain retires 4 nodes instead of 1.

constexpr int N_NODES = 100000;
constexpr int N_EDGES = 3200000;
constexpr int IN_CH  = 13;
constexpr int HID_CH = 32;
constexpr int LAT_CH = 16;

constexpr int NBKT = 196;        // ceil(100000/512) coarse buckets (dst>>9)
constexpr int BCAP = 20480;      // bucket capacity; mean 16384, sd ~128
constexpr int TILE = 16384;      // edges per binA block

__global__ __launch_bounds__(256) void k_zero_bcur(int* __restrict__ bcur) {
    int i = threadIdx.x;
    if (i < NBKT) bcur[i] = 0;
}

// bin edges into coarse bucket regions; packed word = (dst&511)<<17 | src
__global__ __launch_bounds__(1024) void k_binA(const int* __restrict__ src,
                                               const int* __restrict__ dst,
                                               int* __restrict__ bcur,
                                               int* __restrict__ buckets) {
    __shared__ int h[NBKT], st[NBKT], cur[NBKT];
    int tid = threadIdx.x;
    for (int i = tid; i < NBKT; i += 1024) h[i] = 0;
    __syncthreads();
    int e0 = blockIdx.x * TILE;
    for (int i = tid; i < TILE; i += 1024) {
        int e = e0 + i;
        if (e < N_EDGES) atomicAdd(&h[dst[e] >> 9], 1);
    }
    __syncthreads();
    for (int i = tid; i < NBKT; i += 1024) {
        int c = h[i];
        st[i] = c > 0 ? atomicAdd(&bcur[i], c) : 0;
        cur[i] = 0;
    }
    __syncthreads();
    for (int i = tid; i < TILE; i += 1024) {
        int e = e0 + i;
        if (e < N_EDGES) {
            int d = dst[e];
            int b = d >> 9;
            int r = atomicAdd(&cur[b], 1);
            buckets[b * BCAP + st[b] + r] = src[e] | ((d & 511) << 17);
        }
    }
}

// exclusive scan of 196 bucket counts (one tiny block)
__global__ __launch_bounds__(256) void k_scanTop(const int* __restrict__ bcur,
                                                 int* __restrict__ bbase) {
    __shared__ int v[256];
    int tid = threadIdx.x;
    v[tid] = (tid < NBKT) ? bcur[tid] : 0;
    __syncthreads();
    for (int d = 1; d < 256; d <<= 1) {
        int a = v[tid];
        int u = (tid >= d) ? v[tid - d] : 0;
        __syncthreads();
        v[tid] = a + u;
        __syncthreads();
    }
    if (tid < NBKT) bbase[tid] = v[tid] - bcur[tid];
}

// per-bucket counting sort: LDS hist over 512 nodes -> LDS scan -> scatter.
// also emits off[node], dis[node].
__global__ __launch_bounds__(1024) void k_binB(const int* __restrict__ bcur,
                                               const int* __restrict__ bbase,
                                               const int* __restrict__ buckets,
                                               int* __restrict__ off,
                                               float* __restrict__ dis,
                                               int* __restrict__ srcs) {
    __shared__ int h[512], ex[512], curso[512];
    int b = blockIdx.x, tid = threadIdx.x;
    int cntb = bcur[b], base = bbase[b];
    const int* bw = buckets + b * BCAP;
    if (tid < 512) h[tid] = 0;
    __syncthreads();
    for (int i = tid; i < cntb; i += 1024) atomicAdd(&h[bw[i] >> 17], 1);
    __syncthreads();
    int node0 = b * 512;
    if (tid < 512) {
        int node = node0 + tid;
        if (node < N_NODES) dis[node] = rsqrtf((float)(h[tid] + 1));  // +1 self-loop
        ex[tid] = h[tid];
    }
    __syncthreads();
    for (int d = 1; d < 512; d <<= 1) {    // inclusive scan over 512
        int a = 0, u = 0;
        if (tid < 512) a = ex[tid];
        if (tid >= d && tid < 512) u = ex[tid - d];
        __syncthreads();
        if (tid < 512) ex[tid] = a + u;
        __syncthreads();
    }
    if (tid < 512) {
        int excl = ex[tid] - h[tid];
        int node = node0 + tid;
        if (node < N_NODES) off[node] = base + excl;
        curso[tid] = excl;
    }
    if (b == 0 && tid == 0) off[N_NODES] = N_EDGES;
    __syncthreads();
    for (int i = tid; i < cntb; i += 1024) {
        int w = bw[i];
        int r = atomicAdd(&curso[w >> 17], 1);
        srcs[base + r] = w & 131071;
    }
}

// xn[i*16+c] = (c<13 ? x[i*13+c] : 0) * dis[i]
__global__ __launch_bounds__(256) void k_xn(const float* __restrict__ x,
                                            const float* __restrict__ dis,
                                            float* __restrict__ xn) {
    int idx = blockIdx.x * 256 + threadIdx.x;
    if (idx >= N_NODES * 16) return;
    int node = idx >> 4, c = idx & 15;
    xn[idx] = (c < IN_CH) ? x[node * IN_CH + c] * dis[node] : 0.f;
}

// 4 nodes per wave: 16 lanes/node = 4 edge slots x 4 channel-quads, dual
// window (2 float4 gathers in flight/lane), srcs prefetched one window ahead.
// Each off/srcs/gather instruction serves 4 nodes -> 4 nodes amortize one
// latency chain. No atomics.
// outv[d*16+ch] = dis[d] * (sum_edges vin[s*16+ch] + vin[d*16+ch]) (+ bias)
__global__ __launch_bounds__(256) void k_agg(const int* __restrict__ off,
                                             const int* __restrict__ srcs,
                                             const float* __restrict__ dis,
                                             const float* __restrict__ vin,
                                             const float* __restrict__ bias,  // may be null
                                             float* __restrict__ outv) {
    int wave = (blockIdx.x * 256 + threadIdx.x) >> 6;
    int lane = threadIdx.x & 63;
    int q    = lane & 3;           // channel quad: floats q*4 .. q*4+3
    int esub = (lane >> 2) & 3;    // edge slot 0..3 (and +4 for second window)
    int nsub = lane >> 4;          // node sub-index 0..3
    int node = wave * 4 + nsub;
    bool valid = node < N_NODES;
    int beg = valid ? off[node] : 0;
    int end = valid ? off[node + 1] : 0;

    float ax = 0.f, ay = 0.f, az = 0.f, aw = 0.f;
    int k1 = beg + esub;
    int k2 = k1 + 4;
    int s1 = (k1 < end) ? srcs[k1] : -1;
    int s2 = (k2 < end) ? srcs[k2] : -1;
    for (int kb = beg; kb < end; kb += 8) {
        int kn = kb + 8 + esub;
        int sn1 = (kn < end)     ? srcs[kn]     : -1;   // prefetch next window
        int sn2 = (kn + 4 < end) ? srcs[kn + 4] : -1;
        float4 v1, v2;
        v1.x = v1.y = v1.z = v1.w = 0.f;
        v2.x = v2.y = v2.z = v2.w = 0.f;
        if (s1 >= 0) v1 = *((const float4*)(vin + (size_t)s1 * 16) + q);
        if (s2 >= 0) v2 = *((const float4*)(vin + (size_t)s2 * 16) + q);
        ax += v1.x + v2.x;
        ay += v1.y + v2.y;
        az += v1.z + v2.z;
        aw += v1.w + v2.w;
        s1 = sn1; s2 = sn2;
    }
#pragma unroll
    for (int m = 4; m <= 8; m <<= 1) {         // reduce over esub (lane bits 2..3)
        ax += __shfl_xor(ax, m);
        ay += __shfl_xor(ay, m);
        az += __shfl_xor(az, m);
        aw += __shfl_xor(aw, m);
    }
    if (esub == 0 && valid) {                  // 4 nodes x 4 quads = 16 store lanes
        const float4 self = *((const float4*)(vin + (size_t)node * 16) + q);
        float d = dis[node];
        float4 r;
        r.x = d * (ax + self.x);
        r.y = d * (ay + self.y);
        r.z = d * (az + self.z);
        r.w = d * (aw + self.w);
        if (bias) {
            const float4 bq = ((const float4*)bias)[q];
            r.x += bq.x; r.y += bq.y; r.z += bq.z; r.w += bq.w;
        }
        *((float4*)(outv + (size_t)node * 16) + q) = r;
    }
}

// fused: hwn = (relu(s1 @ W1 + b1) @ W2) * dis   (per node, through LDS)
__global__ __launch_bounds__(256) void k_gemm12(const float* __restrict__ s1,
                                                const float* __restrict__ W1,
                                                const float* __restrict__ b1,
                                                const float* __restrict__ W2,
                                                const float* __restrict__ dis,
                                                float* __restrict__ hwn) {
    __shared__ float sW1[IN_CH * HID_CH];
    __shared__ float sW2[HID_CH * LAT_CH];
    __shared__ float sr[8][HID_CH + 1];
    int tid = threadIdx.x;
    for (int i = tid; i < IN_CH * HID_CH; i += 256) sW1[i] = W1[i];
    for (int i = tid; i < HID_CH * LAT_CH; i += 256) sW2[i] = W2[i];
    __syncthreads();
    int nl = tid >> 5, c1 = tid & 31;
    int node = blockIdx.x * 8 + nl;
    float r = 0.f;
    if (node < N_NODES) {
        float acc = b1[c1];
#pragma unroll
        for (int k = 0; k < IN_CH; ++k)
            acc += s1[node * 16 + k] * sW1[k * HID_CH + c1];
        r = acc > 0.f ? acc : 0.f;   // ReLU
    }
    sr[nl][c1] = r;
    __syncthreads();
    if (tid < 128) {
        int nl2 = tid >> 4, c2 = tid & 15;
        int node2 = blockIdx.x * 8 + nl2;
        if (node2 < N_NODES) {
            float acc = 0.f;
#pragma unroll
            for (int k = 0; k < HID_CH; ++k)
                acc += sr[nl2][k] * sW2[k * LAT_CH + c2];
            hwn[node2 * 16 + c2] = acc * dis[node2];
        }
    }
}

extern "C" void kernel_launch(void* const* d_in, const int* in_sizes, int n_in,
                              void* d_out, int out_size, void* d_ws, size_t ws_size,
                              hipStream_t stream) {
    const float* x  = (const float*)d_in[0];
    const int*   ei = (const int*)d_in[1];
    const float* W1 = (const float*)d_in[2];
    const float* b1 = (const float*)d_in[3];
    const float* W2 = (const float*)d_in[4];
    const float* b2 = (const float*)d_in[5];
    float* out = (float*)d_out;

    const int* src = ei;
    const int* dst = ei + N_EDGES;

    // ws layout (bytes):
    //   bcur[196]  @ 0        | bbase[196] @ 1024 | off[N+1] @ 2048
    //   dis[N]     @ 402176   | srcs[E]    @ 802176
    //   buckets    @ 13602176 (196*20480*4) -- dead after binB
    //   xn  aliases buckets; s1 aliases buckets+6.4MB; hwn aliases xn
    char* ws = (char*)d_ws;
    int*   bcur    = (int*)(ws);
    int*   bbase   = (int*)(ws + 1024);
    int*   off     = (int*)(ws + 2048);
    float* dis     = (float*)(ws + 402176);
    int*   srcs    = (int*)(ws + 802176);
    int*   buckets = (int*)(ws + 13602176);
    float* xn      = (float*)(ws + 13602176);
    float* s1      = (float*)(ws + 13602176 + 6400000);
    float* hwn     = xn;  // xn dead after first k_agg

    const int NB_A  = (N_EDGES + TILE - 1) / TILE;      // 196
    const int NB_N16= (N_NODES * 16 + 255) / 256;
    const int NB_W  = (N_NODES + 15) / 16;              // 4 nodes/wave, 4 waves/block
    const int NB_G  = (N_NODES + 7) / 8;

    k_zero_bcur<<<1,    256, 0, stream>>>(bcur);
    k_binA     <<<NB_A, 1024, 0, stream>>>(src, dst, bcur, buckets);
    k_scanTop  <<<1,    256, 0, stream>>>(bcur, bbase);
    k_binB     <<<NBKT, 1024, 0, stream>>>(bcur, bbase, buckets, off, dis, srcs);
    k_xn       <<<NB_N16, 256, 0, stream>>>(x, dis, xn);
    k_agg      <<<NB_W,  256, 0, stream>>>(off, srcs, dis, xn, nullptr, s1);
    k_gemm12   <<<NB_G,  256, 0, stream>>>(s1, W1, b1, W2, dis, hwn);
    k_agg      <<<NB_W,  256, 0, stream>>>(off, srcs, dis, hwn, b2, out);
}

// Round 8
// 229.237 us; speedup vs baseline: 3.5732x; 1.0050x over previous
//
#include <hip/hip_runtime.h>

// GCN 2-layer, N=100000, E=3200000, 13 -> 32 -> 16.
// v7: two-level counting sort re-grained to 392 buckets x 256 nodes (dst>>8),
// TILE=8192 -> binA 392 blocks, binB 392 blocks (full CU coverage, 2x less
// LDS-atomic contention, half-depth scans). k_agg = v3 (4 nodes/wave, best).

constexpr int N_NODES = 100000;
constexpr int N_EDGES = 3200000;
constexpr int IN_CH  = 13;
constexpr int HID_CH = 32;
constexpr int LAT_CH = 16;

constexpr int NPB  = 256;                          // nodes per bucket (dst>>8)
constexpr int NBKT = (N_NODES + NPB - 1) / NPB;    // 392
constexpr int BCAP = 8960;                         // mean 8192, sd ~90 -> +8.5 sigma
constexpr int TILE = 8192;                         // edges per binA block

__global__ __launch_bounds__(512) void k_zero_bcur(int* __restrict__ bcur) {
    int i = threadIdx.x;
    if (i < NBKT) bcur[i] = 0;
}

// bin edges into coarse bucket regions; packed word = (dst&255)<<17 | src
__global__ __launch_bounds__(1024) void k_binA(const int* __restrict__ src,
                                               const int* __restrict__ dst,
                                               int* __restrict__ bcur,
                                               int* __restrict__ buckets) {
    __shared__ int h[NBKT], st[NBKT], cur[NBKT];
    int tid = threadIdx.x;
    for (int i = tid; i < NBKT; i += 1024) h[i] = 0;
    __syncthreads();
    int e0 = blockIdx.x * TILE;
    for (int i = tid; i < TILE; i += 1024) {
        int e = e0 + i;
        if (e < N_EDGES) atomicAdd(&h[dst[e] >> 8], 1);
    }
    __syncthreads();
    for (int i = tid; i < NBKT; i += 1024) {
        int c = h[i];
        st[i] = c > 0 ? atomicAdd(&bcur[i], c) : 0;
        cur[i] = 0;
    }
    __syncthreads();
    for (int i = tid; i < TILE; i += 1024) {
        int e = e0 + i;
        if (e < N_EDGES) {
            int d = dst[e];
            int b = d >> 8;
            int r = atomicAdd(&cur[b], 1);
            buckets[b * BCAP + st[b] + r] = src[e] | ((d & 255) << 17);
        }
    }
}

// exclusive scan of 392 bucket counts (one 512-thread block)
__global__ __launch_bounds__(512) void k_scanTop(const int* __restrict__ bcur,
                                                 int* __restrict__ bbase) {
    __shared__ int v[512];
    int tid = threadIdx.x;
    v[tid] = (tid < NBKT) ? bcur[tid] : 0;
    __syncthreads();
    for (int d = 1; d < 512; d <<= 1) {
        int a = v[tid];
        int u = (tid >= d) ? v[tid - d] : 0;
        __syncthreads();
        v[tid] = a + u;
        __syncthreads();
    }
    if (tid < NBKT) bbase[tid] = v[tid] - bcur[tid];
}

// per-bucket counting sort: LDS hist over 256 nodes -> LDS scan -> scatter.
// also emits off[node], dis[node].
__global__ __launch_bounds__(1024) void k_binB(const int* __restrict__ bcur,
                                               const int* __restrict__ bbase,
                                               const int* __restrict__ buckets,
                                               int* __restrict__ off,
                                               float* __restrict__ dis,
                                               int* __restrict__ srcs) {
    __shared__ int h[NPB], ex[NPB], curso[NPB];
    int b = blockIdx.x, tid = threadIdx.x;
    int cntb = bcur[b], base = bbase[b];
    const int* bw = buckets + b * BCAP;
    if (tid < NPB) h[tid] = 0;
    __syncthreads();
    for (int i = tid; i < cntb; i += 1024) atomicAdd(&h[bw[i] >> 17], 1);
    __syncthreads();
    int node0 = b * NPB;
    if (tid < NPB) {
        int node = node0 + tid;
        if (node < N_NODES) dis[node] = rsqrtf((float)(h[tid] + 1));  // +1 self-loop
        ex[tid] = h[tid];
    }
    __syncthreads();
    for (int d = 1; d < NPB; d <<= 1) {    // inclusive scan over 256
        int a = 0, u = 0;
        if (tid < NPB) a = ex[tid];
        if (tid >= d && tid < NPB) u = ex[tid - d];
        __syncthreads();
        if (tid < NPB) ex[tid] = a + u;
        __syncthreads();
    }
    if (tid < NPB) {
        int excl = ex[tid] - h[tid];
        int node = node0 + tid;
        if (node < N_NODES) off[node] = base + excl;
        curso[tid] = excl;
    }
    if (b == 0 && tid == 0) off[N_NODES] = N_EDGES;
    __syncthreads();
    for (int i = tid; i < cntb; i += 1024) {
        int w = bw[i];
        int r = atomicAdd(&curso[w >> 17], 1);
        srcs[base + r] = w & 131071;
    }
}

// xn[i*16+c] = (c<13 ? x[i*13+c] : 0) * dis[i]
__global__ __launch_bounds__(256) void k_xn(const float* __restrict__ x,
                                            const float* __restrict__ dis,
                                            float* __restrict__ xn) {
    int idx = blockIdx.x * 256 + threadIdx.x;
    if (idx >= N_NODES * 16) return;
    int node = idx >> 4, c = idx & 15;
    xn[idx] = (c < IN_CH) ? x[node * IN_CH + c] * dis[node] : 0.f;
}

// 4 nodes per wave: 16 lanes/node = 4 edge slots x 4 channel-quads, dual
// window (2 float4 gathers in flight/lane), srcs prefetched one window ahead.
// outv[d*16+ch] = dis[d] * (sum_edges vin[s*16+ch] + vin[d*16+ch]) (+ bias)
__global__ __launch_bounds__(256) void k_agg(const int* __restrict__ off,
                                             const int* __restrict__ srcs,
                                             const float* __restrict__ dis,
                                             const float* __restrict__ vin,
                                             const float* __restrict__ bias,  // may be null
                                             float* __restrict__ outv) {
    int wave = (blockIdx.x * 256 + threadIdx.x) >> 6;
    int lane = threadIdx.x & 63;
    int q    = lane & 3;           // channel quad: floats q*4 .. q*4+3
    int esub = (lane >> 2) & 3;    // edge slot 0..3 (and +4 for second window)
    int nsub = lane >> 4;          // node sub-index 0..3
    int node = wave * 4 + nsub;
    bool valid = node < N_NODES;
    int beg = valid ? off[node] : 0;
    int end = valid ? off[node + 1] : 0;

    float ax = 0.f, ay = 0.f, az = 0.f, aw = 0.f;
    int k1 = beg + esub;
    int k2 = k1 + 4;
    int s1 = (k1 < end) ? srcs[k1] : -1;
    int s2 = (k2 < end) ? srcs[k2] : -1;
    for (int kb = beg; kb < end; kb += 8) {
        int kn = kb + 8 + esub;
        int sn1 = (kn < end)     ? srcs[kn]     : -1;   // prefetch next window
        int sn2 = (kn + 4 < end) ? srcs[kn + 4] : -1;
        float4 v1, v2;
        v1.x = v1.y = v1.z = v1.w = 0.f;
        v2.x = v2.y = v2.z = v2.w = 0.f;
        if (s1 >= 0) v1 = *((const float4*)(vin + (size_t)s1 * 16) + q);
        if (s2 >= 0) v2 = *((const float4*)(vin + (size_t)s2 * 16) + q);
        ax += v1.x + v2.x;
        ay += v1.y + v2.y;
        az += v1.z + v2.z;
        aw += v1.w + v2.w;
        s1 = sn1; s2 = sn2;
    }
#pragma unroll
    for (int m = 4; m <= 8; m <<= 1) {         // reduce over esub (lane bits 2..3)
        ax += __shfl_xor(ax, m);
        ay += __shfl_xor(ay, m);
        az += __shfl_xor(az, m);
        aw += __shfl_xor(aw, m);
    }
    if (esub == 0 && valid) {                  // 4 nodes x 4 quads = 16 store lanes
        const float4 self = *((const float4*)(vin + (size_t)node * 16) + q);
        float d = dis[node];
        float4 r;
        r.x = d * (ax + self.x);
        r.y = d * (ay + self.y);
        r.z = d * (az + self.z);
        r.w = d * (aw + self.w);
        if (bias) {
            const float4 bq = ((const float4*)bias)[q];
            r.x += bq.x; r.y += bq.y; r.z += bq.z; r.w += bq.w;
        }
        *((float4*)(outv + (size_t)node * 16) + q) = r;
    }
}

// fused: hwn = (relu(s1 @ W1 + b1) @ W2) * dis   (per node, through LDS)
__global__ __launch_bounds__(256) void k_gemm12(const float* __restrict__ s1,
                                                const float* __restrict__ W1,
                                                const float* __restrict__ b1,
                                                const float* __restrict__ W2,
                                                const float* __restrict__ dis,
                                                float* __restrict__ hwn) {
    __shared__ float sW1[IN_CH * HID_CH];
    __shared__ float sW2[HID_CH * LAT_CH];
    __shared__ float sr[8][HID_CH + 1];
    int tid = threadIdx.x;
    for (int i = tid; i < IN_CH * HID_CH; i += 256) sW1[i] = W1[i];
    for (int i = tid; i < HID_CH * LAT_CH; i += 256) sW2[i] = W2[i];
    __syncthreads();
    int nl = tid >> 5, c1 = tid & 31;
    int node = blockIdx.x * 8 + nl;
    float r = 0.f;
    if (node < N_NODES) {
        float acc = b1[c1];
#pragma unroll
        for (int k = 0; k < IN_CH; ++k)
            acc += s1[node * 16 + k] * sW1[k * HID_CH + c1];
        r = acc > 0.f ? acc : 0.f;   // ReLU
    }
    sr[nl][c1] = r;
    __syncthreads();
    if (tid < 128) {
        int nl2 = tid >> 4, c2 = tid & 15;
        int node2 = blockIdx.x * 8 + nl2;
        if (node2 < N_NODES) {
            float acc = 0.f;
#pragma unroll
            for (int k = 0; k < HID_CH; ++k)
                acc += sr[nl2][k] * sW2[k * LAT_CH + c2];
            hwn[node2 * 16 + c2] = acc * dis[node2];
        }
    }
}

extern "C" void kernel_launch(void* const* d_in, const int* in_sizes, int n_in,
                              void* d_out, int out_size, void* d_ws, size_t ws_size,
                              hipStream_t stream) {
    const float* x  = (const float*)d_in[0];
    const int*   ei = (const int*)d_in[1];
    const float* W1 = (const float*)d_in[2];
    const float* b1 = (const float*)d_in[3];
    const float* W2 = (const float*)d_in[4];
    const float* b2 = (const float*)d_in[5];
    float* out = (float*)d_out;

    const int* src = ei;
    const int* dst = ei + N_EDGES;

    // ws layout (bytes):
    //   bcur[392]  @ 0     | bbase[392] @ 2048 | off[N+1] @ 4096
    //   dis[N]     @ 404160 | srcs[E] @ 804160
    //   buckets    @ 13604160 (392*8960*4 = 14,049,280) -- dead after binB
    //   xn aliases buckets; s1 @ buckets+6.4MB; hwn aliases xn
    char* ws = (char*)d_ws;
    int*   bcur    = (int*)(ws);
    int*   bbase   = (int*)(ws + 2048);
    int*   off     = (int*)(ws + 4096);
    float* dis     = (float*)(ws + 404160);
    int*   srcs    = (int*)(ws + 804160);
    int*   buckets = (int*)(ws + 13604160);
    float* xn      = (float*)(ws + 13604160);
    float* s1      = (float*)(ws + 13604160 + 6400000);
    float* hwn     = xn;  // xn dead after first k_agg

    const int NB_A  = (N_EDGES + TILE - 1) / TILE;      // 391
    const int NB_N16= (N_NODES * 16 + 255) / 256;
    const int NB_W  = (N_NODES + 15) / 16;              // 4 nodes/wave, 4 waves/block
    const int NB_G  = (N_NODES + 7) / 8;

    k_zero_bcur<<<1,    512, 0, stream>>>(bcur);
    k_binA     <<<NB_A, 1024, 0, stream>>>(src, dst, bcur, buckets);
    k_scanTop  <<<1,    512, 0, stream>>>(bcur, bbase);
    k_binB     <<<NBKT, 1024, 0, stream>>>(bcur, bbase, buckets, off, dis, srcs);
    k_xn       <<<NB_N16, 256, 0, stream>>>(x, dis, xn);
    k_agg      <<<NB_W,  256, 0, stream>>>(off, srcs, dis, xn, nullptr, s1);
    k_gemm12   <<<NB_G,  256, 0, stream>>>(s1, W1, b1, W2, dis, hwn);
    k_agg      <<<NB_W,  256, 0, stream>>>(off, srcs, dis, hwn, b2, out);
}

// Round 9
// 220.446 us; speedup vs baseline: 3.7157x; 1.0399x over previous
//
#include <hip/hip_runtime.h>

// GCN 2-layer, N=100000, E=3200000, 13 -> 32 -> 16.
// v8: binA = 512thr/TILE4096 (782 blocks, 76% occ), single edge-list pass via
// int4 register staging. binB = LDS-staged bucket, LDS->LDS sort scatter,
// coalesced srcs write. k_agg = v3 (4 nodes/wave). Sort granularity 392x256.

constexpr int N_NODES = 100000;
constexpr int N_EDGES = 3200000;
constexpr int IN_CH  = 13;
constexpr int HID_CH = 32;
constexpr int LAT_CH = 16;

constexpr int NPB  = 256;                          // nodes per bucket (dst>>8)
constexpr int NBKT = (N_NODES + NPB - 1) / NPB;    // 392
constexpr int BCAP = 8960;                         // mean 8192, sd ~90 -> +8.5 sigma
constexpr int TILE = 4096;                         // edges per binA block (8/thread)

__global__ __launch_bounds__(512) void k_zero_bcur(int* __restrict__ bcur) {
    int i = threadIdx.x;
    if (i < NBKT) bcur[i] = 0;
}

// bin edges into coarse bucket regions; packed word = (dst&255)<<17 | src.
// One pass over the edge list: 8 edges/thread staged in registers (int4 x2).
__global__ __launch_bounds__(512) void k_binA(const int* __restrict__ src,
                                              const int* __restrict__ dst,
                                              int* __restrict__ bcur,
                                              int* __restrict__ buckets) {
    __shared__ int h[NBKT], st[NBKT], cur[NBKT];
    int tid = threadIdx.x;
    for (int i = tid; i < NBKT; i += 512) h[i] = 0;
    __syncthreads();
    int base8 = blockIdx.x * TILE + tid * 8;       // TILE = 512*8; groups never split
    int d[8], s[8];
    bool have = base8 < N_EDGES;
    if (have) {
        const int4* dp = (const int4*)(dst + base8);
        const int4* sp = (const int4*)(src + base8);
        int4 d0 = dp[0], d1 = dp[1];
        int4 s0 = sp[0], s1 = sp[1];
        d[0]=d0.x; d[1]=d0.y; d[2]=d0.z; d[3]=d0.w;
        d[4]=d1.x; d[5]=d1.y; d[6]=d1.z; d[7]=d1.w;
        s[0]=s0.x; s[1]=s0.y; s[2]=s0.z; s[3]=s0.w;
        s[4]=s1.x; s[5]=s1.y; s[6]=s1.z; s[7]=s1.w;
#pragma unroll
        for (int j = 0; j < 8; ++j) atomicAdd(&h[d[j] >> 8], 1);
    }
    __syncthreads();
    for (int i = tid; i < NBKT; i += 512) {
        int c = h[i];
        st[i] = c > 0 ? atomicAdd(&bcur[i], c) : 0;
        cur[i] = 0;
    }
    __syncthreads();
    if (have) {
#pragma unroll
        for (int j = 0; j < 8; ++j) {
            int b = d[j] >> 8;
            int r = atomicAdd(&cur[b], 1);
            buckets[b * BCAP + st[b] + r] = s[j] | ((d[j] & 255) << 17);
        }
    }
}

// exclusive scan of 392 bucket counts (one 512-thread block)
__global__ __launch_bounds__(512) void k_scanTop(const int* __restrict__ bcur,
                                                 int* __restrict__ bbase) {
    __shared__ int v[512];
    int tid = threadIdx.x;
    v[tid] = (tid < NBKT) ? bcur[tid] : 0;
    __syncthreads();
    for (int d = 1; d < 512; d <<= 1) {
        int a = v[tid];
        int u = (tid >= d) ? v[tid - d] : 0;
        __syncthreads();
        v[tid] = a + u;
        __syncthreads();
    }
    if (tid < NBKT) bbase[tid] = v[tid] - bcur[tid];
}

// per-bucket counting sort, fully in LDS: stage bucket words (1 coalesced
// global read), LDS hist over 256 nodes, LDS scan, LDS->LDS scatter, then
// coalesced srcs write. Emits off[node], dis[node].
__global__ __launch_bounds__(512) void k_binB(const int* __restrict__ bcur,
                                              const int* __restrict__ bbase,
                                              const int* __restrict__ buckets,
                                              int* __restrict__ off,
                                              float* __restrict__ dis,
                                              int* __restrict__ srcs) {
    __shared__ int wbuf[BCAP];     // staged bucket words
    __shared__ int sorted_[BCAP];  // sorted src ids
    __shared__ int h[NPB], ex[NPB], curso[NPB];
    int b = blockIdx.x, tid = threadIdx.x;
    int cntb = bcur[b], base = bbase[b];
    if (cntb > BCAP) cntb = BCAP;
    const int* bw = buckets + b * BCAP;
    for (int i = tid; i < cntb; i += 512) wbuf[i] = bw[i];
    if (tid < NPB) h[tid] = 0;
    __syncthreads();
    for (int i = tid; i < cntb; i += 512) atomicAdd(&h[wbuf[i] >> 17], 1);
    __syncthreads();
    int node0 = b * NPB;
    if (tid < NPB) {
        int node = node0 + tid;
        if (node < N_NODES) dis[node] = rsqrtf((float)(h[tid] + 1));  // +1 self-loop
        ex[tid] = h[tid];
    }
    __syncthreads();
    for (int d = 1; d < NPB; d <<= 1) {    // inclusive scan over 256
        int a = 0, u = 0;
        if (tid < NPB) a = ex[tid];
        if (tid >= d && tid < NPB) u = ex[tid - d];
        __syncthreads();
        if (tid < NPB) ex[tid] = a + u;
        __syncthreads();
    }
    if (tid < NPB) {
        int excl = ex[tid] - h[tid];
        int node = node0 + tid;
        if (node < N_NODES) off[node] = base + excl;
        curso[tid] = excl;
    }
    if (b == 0 && tid == 0) off[N_NODES] = N_EDGES;
    __syncthreads();
    for (int i = tid; i < cntb; i += 512) {
        int w = wbuf[i];
        int r = atomicAdd(&curso[w >> 17], 1);
        sorted_[r] = w & 131071;
    }
    __syncthreads();
    for (int i = tid; i < cntb; i += 512) srcs[base + i] = sorted_[i];
}

// xn[i*16+c] = (c<13 ? x[i*13+c] : 0) * dis[i]
__global__ __launch_bounds__(256) void k_xn(const float* __restrict__ x,
                                            const float* __restrict__ dis,
                                            float* __restrict__ xn) {
    int idx = blockIdx.x * 256 + threadIdx.x;
    if (idx >= N_NODES * 16) return;
    int node = idx >> 4, c = idx & 15;
    xn[idx] = (c < IN_CH) ? x[node * IN_CH + c] * dis[node] : 0.f;
}

// 4 nodes per wave: 16 lanes/node = 4 edge slots x 4 channel-quads, dual
// window (2 float4 gathers in flight/lane), srcs prefetched one window ahead.
// outv[d*16+ch] = dis[d] * (sum_edges vin[s*16+ch] + vin[d*16+ch]) (+ bias)
__global__ __launch_bounds__(256) void k_agg(const int* __restrict__ off,
                                             const int* __restrict__ srcs,
                                             const float* __restrict__ dis,
                                             const float* __restrict__ vin,
                                             const float* __restrict__ bias,  // may be null
                                             float* __restrict__ outv) {
    int wave = (blockIdx.x * 256 + threadIdx.x) >> 6;
    int lane = threadIdx.x & 63;
    int q    = lane & 3;           // channel quad: floats q*4 .. q*4+3
    int esub = (lane >> 2) & 3;    // edge slot 0..3 (and +4 for second window)
    int nsub = lane >> 4;          // node sub-index 0..3
    int node = wave * 4 + nsub;
    bool valid = node < N_NODES;
    int beg = valid ? off[node] : 0;
    int end = valid ? off[node + 1] : 0;

    float ax = 0.f, ay = 0.f, az = 0.f, aw = 0.f;
    int k1 = beg + esub;
    int k2 = k1 + 4;
    int s1 = (k1 < end) ? srcs[k1] : -1;
    int s2 = (k2 < end) ? srcs[k2] : -1;
    for (int kb = beg; kb < end; kb += 8) {
        int kn = kb + 8 + esub;
        int sn1 = (kn < end)     ? srcs[kn]     : -1;   // prefetch next window
        int sn2 = (kn + 4 < end) ? srcs[kn + 4] : -1;
        float4 v1, v2;
        v1.x = v1.y = v1.z = v1.w = 0.f;
        v2.x = v2.y = v2.z = v2.w = 0.f;
        if (s1 >= 0) v1 = *((const float4*)(vin + (size_t)s1 * 16) + q);
        if (s2 >= 0) v2 = *((const float4*)(vin + (size_t)s2 * 16) + q);
        ax += v1.x + v2.x;
        ay += v1.y + v2.y;
        az += v1.z + v2.z;
        aw += v1.w + v2.w;
        s1 = sn1; s2 = sn2;
    }
#pragma unroll
    for (int m = 4; m <= 8; m <<= 1) {         // reduce over esub (lane bits 2..3)
        ax += __shfl_xor(ax, m);
        ay += __shfl_xor(ay, m);
        az += __shfl_xor(az, m);
        aw += __shfl_xor(aw, m);
    }
    if (esub == 0 && valid) {                  // 4 nodes x 4 quads = 16 store lanes
        const float4 self = *((const float4*)(vin + (size_t)node * 16) + q);
        float d = dis[node];
        float4 r;
        r.x = d * (ax + self.x);
        r.y = d * (ay + self.y);
        r.z = d * (az + self.z);
        r.w = d * (aw + self.w);
        if (bias) {
            const float4 bq = ((const float4*)bias)[q];
            r.x += bq.x; r.y += bq.y; r.z += bq.z; r.w += bq.w;
        }
        *((float4*)(outv + (size_t)node * 16) + q) = r;
    }
}

// fused: hwn = (relu(s1 @ W1 + b1) @ W2) * dis   (per node, through LDS)
__global__ __launch_bounds__(256) void k_gemm12(const float* __restrict__ s1,
                                                const float* __restrict__ W1,
                                                const float* __restrict__ b1,
                                                const float* __restrict__ W2,
                                                const float* __restrict__ dis,
                                                float* __restrict__ hwn) {
    __shared__ float sW1[IN_CH * HID_CH];
    __shared__ float sW2[HID_CH * LAT_CH];
    __shared__ float sr[8][HID_CH + 1];
    int tid = threadIdx.x;
    for (int i = tid; i < IN_CH * HID_CH; i += 256) sW1[i] = W1[i];
    for (int i = tid; i < HID_CH * LAT_CH; i += 256) sW2[i] = W2[i];
    __syncthreads();
    int nl = tid >> 5, c1 = tid & 31;
    int node = blockIdx.x * 8 + nl;
    float r = 0.f;
    if (node < N_NODES) {
        float acc = b1[c1];
#pragma unroll
        for (int k = 0; k < IN_CH; ++k)
            acc += s1[node * 16 + k] * sW1[k * HID_CH + c1];
        r = acc > 0.f ? acc : 0.f;   // ReLU
    }
    sr[nl][c1] = r;
    __syncthreads();
    if (tid < 128) {
        int nl2 = tid >> 4, c2 = tid & 15;
        int node2 = blockIdx.x * 8 + nl2;
        if (node2 < N_NODES) {
            float acc = 0.f;
#pragma unroll
            for (int k = 0; k < HID_CH; ++k)
                acc += sr[nl2][k] * sW2[k * LAT_CH + c2];
            hwn[node2 * 16 + c2] = acc * dis[node2];
        }
    }
}

extern "C" void kernel_launch(void* const* d_in, const int* in_sizes, int n_in,
                              void* d_out, int out_size, void* d_ws, size_t ws_size,
                              hipStream_t stream) {
    const float* x  = (const float*)d_in[0];
    const int*   ei = (const int*)d_in[1];
    const float* W1 = (const float*)d_in[2];
    const float* b1 = (const float*)d_in[3];
    const float* W2 = (const float*)d_in[4];
    const float* b2 = (const float*)d_in[5];
    float* out = (float*)d_out;

    const int* src = ei;
    const int* dst = ei + N_EDGES;

    // ws layout (bytes):
    //   bcur[392]  @ 0     | bbase[392] @ 2048 | off[N+1] @ 4096
    //   dis[N]     @ 404160 | srcs[E] @ 804160
    //   buckets    @ 13604160 (392*8960*4 = 14,049,280) -- dead after binB
    //   xn aliases buckets; s1 @ buckets+6.4MB; hwn aliases xn
    char* ws = (char*)d_ws;
    int*   bcur    = (int*)(ws);
    int*   bbase   = (int*)(ws + 2048);
    int*   off     = (int*)(ws + 4096);
    float* dis     = (float*)(ws + 404160);
    int*   srcs    = (int*)(ws + 804160);
    int*   buckets = (int*)(ws + 13604160);
    float* xn      = (float*)(ws + 13604160);
    float* s1      = (float*)(ws + 13604160 + 6400000);
    float* hwn     = xn;  // xn dead after first k_agg

    const int NB_A  = (N_EDGES + TILE - 1) / TILE;      // 782
    const int NB_N16= (N_NODES * 16 + 255) / 256;
    const int NB_W  = (N_NODES + 15) / 16;              // 4 nodes/wave, 4 waves/block
    const int NB_G  = (N_NODES + 7) / 8;

    k_zero_bcur<<<1,    512, 0, stream>>>(bcur);
    k_binA     <<<NB_A, 512, 0, stream>>>(src, dst, bcur, buckets);
    k_scanTop  <<<1,    512, 0, stream>>>(bcur, bbase);
    k_binB     <<<NBKT, 512, 0, stream>>>(bcur, bbase, buckets, off, dis, srcs);
    k_xn       <<<NB_N16, 256, 0, stream>>>(x, dis, xn);
    k_agg      <<<NB_W,  256, 0, stream>>>(off, srcs, dis, xn, nullptr, s1);
    k_gemm12   <<<NB_G,  256, 0, stream>>>(s1, W1, b1, W2, dis, hwn);
    k_agg      <<<NB_W,  256, 0, stream>>>(off, srcs, dis, hwn, b2, out);
}

// Round 10
// 213.944 us; speedup vs baseline: 3.8286x; 1.0304x over previous
//
#include <hip/hip_runtime.h>

// GCN 2-layer, N=100000, E=3200000, 13 -> 32 -> 16.
// v9: 6-launch pipeline. binB absorbs scanTop (local 391-scan of bcur) and
// k_xn (emits xn rows for its 256 nodes). binA/agg/gemm12 = v8 (best).
// xn moved out of bucket aliasing (binB now writes xn while buckets live).

constexpr int N_NODES = 100000;
constexpr int N_EDGES = 3200000;
constexpr int IN_CH  = 13;
constexpr int HID_CH = 32;
constexpr int LAT_CH = 16;

constexpr int NPB  = 256;                          // nodes per bucket (dst>>8)
constexpr int NBKT = (N_NODES + NPB - 1) / NPB;    // 391
constexpr int BCAP = 8960;                         // mean 8192, sd ~90 -> +8.5 sigma
constexpr int TILE = 4096;                         // edges per binA block (8/thread)

__global__ __launch_bounds__(512) void k_zero_bcur(int* __restrict__ bcur) {
    int i = threadIdx.x;
    if (i < NBKT) bcur[i] = 0;
}

// bin edges into coarse bucket regions; packed word = (dst&255)<<17 | src.
// One pass over the edge list: 8 edges/thread staged in registers (int4 x2).
__global__ __launch_bounds__(512) void k_binA(const int* __restrict__ src,
                                              const int* __restrict__ dst,
                                              int* __restrict__ bcur,
                                              int* __restrict__ buckets) {
    __shared__ int h[NBKT], st[NBKT], cur[NBKT];
    int tid = threadIdx.x;
    for (int i = tid; i < NBKT; i += 512) h[i] = 0;
    __syncthreads();
    int base8 = blockIdx.x * TILE + tid * 8;       // TILE = 512*8; groups never split
    int d[8], s[8];
    bool have = base8 < N_EDGES;
    if (have) {
        const int4* dp = (const int4*)(dst + base8);
        const int4* sp = (const int4*)(src + base8);
        int4 d0 = dp[0], d1 = dp[1];
        int4 s0 = sp[0], s1 = sp[1];
        d[0]=d0.x; d[1]=d0.y; d[2]=d0.z; d[3]=d0.w;
        d[4]=d1.x; d[5]=d1.y; d[6]=d1.z; d[7]=d1.w;
        s[0]=s0.x; s[1]=s0.y; s[2]=s0.z; s[3]=s0.w;
        s[4]=s1.x; s[5]=s1.y; s[6]=s1.z; s[7]=s1.w;
#pragma unroll
        for (int j = 0; j < 8; ++j) atomicAdd(&h[d[j] >> 8], 1);
    }
    __syncthreads();
    for (int i = tid; i < NBKT; i += 512) {
        int c = h[i];
        st[i] = c > 0 ? atomicAdd(&bcur[i], c) : 0;
        cur[i] = 0;
    }
    __syncthreads();
    if (have) {
#pragma unroll
        for (int j = 0; j < 8; ++j) {
            int b = d[j] >> 8;
            int r = atomicAdd(&cur[b], 1);
            buckets[b * BCAP + st[b] + r] = s[j] | ((d[j] & 255) << 17);
        }
    }
}

// per-bucket counting sort, fully in LDS, with fused top-scan and xn emission:
//  - local Hillis-Steele scan of bcur[0..390] gives this bucket's CSR base
//  - stage bucket words (1 coalesced read), LDS hist/scan/scatter
//  - coalesced srcs write; off[node], dis[node]
//  - xn[node][0..15] = (c<13 ? x*dis : 0) for this bucket's 256 nodes
__global__ __launch_bounds__(512) void k_binB(const int* __restrict__ bcur,
                                              const int* __restrict__ buckets,
                                              const float* __restrict__ x,
                                              int* __restrict__ off,
                                              float* __restrict__ dis,
                                              int* __restrict__ srcs,
                                              float* __restrict__ xn) {
    __shared__ int wbuf[BCAP];     // staged bucket words
    __shared__ int sorted_[BCAP];  // sorted src ids
    __shared__ int h[NPB], ex[NPB], curso[NPB];
    __shared__ int sv[512];        // top-level scan buffer
    __shared__ float sdis[NPB];
    int b = blockIdx.x, tid = threadIdx.x;

    // local top scan (inclusive over 512 slots, zeros beyond NBKT)
    sv[tid] = (tid < NBKT) ? bcur[tid] : 0;
    __syncthreads();
    for (int d = 1; d < 512; d <<= 1) {
        int a = sv[tid];
        int u = (tid >= d) ? sv[tid - d] : 0;
        __syncthreads();
        sv[tid] = a + u;
        __syncthreads();
    }
    int base = (b > 0) ? sv[b - 1] : 0;     // exclusive prefix for bucket b
    int cntb = bcur[b];
    if (cntb > BCAP) cntb = BCAP;
    const int* bw = buckets + b * BCAP;

    for (int i = tid; i < cntb; i += 512) wbuf[i] = bw[i];
    if (tid < NPB) h[tid] = 0;
    __syncthreads();
    for (int i = tid; i < cntb; i += 512) atomicAdd(&h[wbuf[i] >> 17], 1);
    __syncthreads();
    int node0 = b * NPB;
    if (tid < NPB) {
        int node = node0 + tid;
        float dv = rsqrtf((float)(h[tid] + 1));   // +1 self-loop
        sdis[tid] = dv;
        if (node < N_NODES) dis[node] = dv;
        ex[tid] = h[tid];
    }
    __syncthreads();
    for (int d = 1; d < NPB; d <<= 1) {    // inclusive scan over 256
        int a = 0, u = 0;
        if (tid < NPB) a = ex[tid];
        if (tid >= d && tid < NPB) u = ex[tid - d];
        __syncthreads();
        if (tid < NPB) ex[tid] = a + u;
        __syncthreads();
    }
    if (tid < NPB) {
        int excl = ex[tid] - h[tid];
        int node = node0 + tid;
        if (node < N_NODES) off[node] = base + excl;
        curso[tid] = excl;
    }
    if (b == 0 && tid == 0) off[N_NODES] = N_EDGES;
    __syncthreads();
    for (int i = tid; i < cntb; i += 512) {
        int w = wbuf[i];
        int r = atomicAdd(&curso[w >> 17], 1);
        sorted_[r] = w & 131071;
    }
    __syncthreads();
    for (int i = tid; i < cntb; i += 512) srcs[base + i] = sorted_[i];
    // fused xn emission for this bucket's nodes (sdis stable since scan barriers)
    for (int i = tid; i < NPB * 16; i += 512) {
        int nl = i >> 4, c = i & 15;
        int node = node0 + nl;
        if (node < N_NODES)
            xn[node * 16 + c] = (c < IN_CH) ? x[node * IN_CH + c] * sdis[nl] : 0.f;
    }
}

// 4 nodes per wave: 16 lanes/node = 4 edge slots x 4 channel-quads, dual
// window (2 float4 gathers in flight/lane), srcs prefetched one window ahead.
// outv[d*16+ch] = dis[d] * (sum_edges vin[s*16+ch] + vin[d*16+ch]) (+ bias)
__global__ __launch_bounds__(256) void k_agg(const int* __restrict__ off,
                                             const int* __restrict__ srcs,
                                             const float* __restrict__ dis,
                                             const float* __restrict__ vin,
                                             const float* __restrict__ bias,  // may be null
                                             float* __restrict__ outv) {
    int wave = (blockIdx.x * 256 + threadIdx.x) >> 6;
    int lane = threadIdx.x & 63;
    int q    = lane & 3;           // channel quad: floats q*4 .. q*4+3
    int esub = (lane >> 2) & 3;    // edge slot 0..3 (and +4 for second window)
    int nsub = lane >> 4;          // node sub-index 0..3
    int node = wave * 4 + nsub;
    bool valid = node < N_NODES;
    int beg = valid ? off[node] : 0;
    int end = valid ? off[node + 1] : 0;

    float ax = 0.f, ay = 0.f, az = 0.f, aw = 0.f;
    int k1 = beg + esub;
    int k2 = k1 + 4;
    int s1 = (k1 < end) ? srcs[k1] : -1;
    int s2 = (k2 < end) ? srcs[k2] : -1;
    for (int kb = beg; kb < end; kb += 8) {
        int kn = kb + 8 + esub;
        int sn1 = (kn < end)     ? srcs[kn]     : -1;   // prefetch next window
        int sn2 = (kn + 4 < end) ? srcs[kn + 4] : -1;
        float4 v1, v2;
        v1.x = v1.y = v1.z = v1.w = 0.f;
        v2.x = v2.y = v2.z = v2.w = 0.f;
        if (s1 >= 0) v1 = *((const float4*)(vin + (size_t)s1 * 16) + q);
        if (s2 >= 0) v2 = *((const float4*)(vin + (size_t)s2 * 16) + q);
        ax += v1.x + v2.x;
        ay += v1.y + v2.y;
        az += v1.z + v2.z;
        aw += v1.w + v2.w;
        s1 = sn1; s2 = sn2;
    }
#pragma unroll
    for (int m = 4; m <= 8; m <<= 1) {         // reduce over esub (lane bits 2..3)
        ax += __shfl_xor(ax, m);
        ay += __shfl_xor(ay, m);
        az += __shfl_xor(az, m);
        aw += __shfl_xor(aw, m);
    }
    if (esub == 0 && valid) {                  // 4 nodes x 4 quads = 16 store lanes
        const float4 self = *((const float4*)(vin + (size_t)node * 16) + q);
        float d = dis[node];
        float4 r;
        r.x = d * (ax + self.x);
        r.y = d * (ay + self.y);
        r.z = d * (az + self.z);
        r.w = d * (aw + self.w);
        if (bias) {
            const float4 bq = ((const float4*)bias)[q];
            r.x += bq.x; r.y += bq.y; r.z += bq.z; r.w += bq.w;
        }
        *((float4*)(outv + (size_t)node * 16) + q) = r;
    }
}

// fused: hwn = (relu(s1 @ W1 + b1) @ W2) * dis   (per node, through LDS)
__global__ __launch_bounds__(256) void k_gemm12(const float* __restrict__ s1,
                                                const float* __restrict__ W1,
                                                const float* __restrict__ b1,
                                                const float* __restrict__ W2,
                                                const float* __restrict__ dis,
                                                float* __restrict__ hwn) {
    __shared__ float sW1[IN_CH * HID_CH];
    __shared__ float sW2[HID_CH * LAT_CH];
    __shared__ float sr[8][HID_CH + 1];
    int tid = threadIdx.x;
    for (int i = tid; i < IN_CH * HID_CH; i += 256) sW1[i] = W1[i];
    for (int i = tid; i < HID_CH * LAT_CH; i += 256) sW2[i] = W2[i];
    __syncthreads();
    int nl = tid >> 5, c1 = tid & 31;
    int node = blockIdx.x * 8 + nl;
    float r = 0.f;
    if (node < N_NODES) {
        float acc = b1[c1];
#pragma unroll
        for (int k = 0; k < IN_CH; ++k)
            acc += s1[node * 16 + k] * sW1[k * HID_CH + c1];
        r = acc > 0.f ? acc : 0.f;   // ReLU
    }
    sr[nl][c1] = r;
    __syncthreads();
    if (tid < 128) {
        int nl2 = tid >> 4, c2 = tid & 15;
        int node2 = blockIdx.x * 8 + nl2;
        if (node2 < N_NODES) {
            float acc = 0.f;
#pragma unroll
            for (int k = 0; k < HID_CH; ++k)
                acc += sr[nl2][k] * sW2[k * LAT_CH + c2];
            hwn[node2 * 16 + c2] = acc * dis[node2];
        }
    }
}

extern "C" void kernel_launch(void* const* d_in, const int* in_sizes, int n_in,
                              void* d_out, int out_size, void* d_ws, size_t ws_size,
                              hipStream_t stream) {
    const float* x  = (const float*)d_in[0];
    const int*   ei = (const int*)d_in[1];
    const float* W1 = (const float*)d_in[2];
    const float* b1 = (const float*)d_in[3];
    const float* W2 = (const float*)d_in[4];
    const float* b2 = (const float*)d_in[5];
    float* out = (float*)d_out;

    const int* src = ei;
    const int* dst = ei + N_EDGES;

    // ws layout (bytes):
    //   bcur[391] @ 0 (pad 4096) | off[N+1] @ 4096 | dis[N] @ 404160
    //   srcs[E]   @ 804160 (12.8MB)
    //   buckets   @ 13604160 (391*8960*4 = 14,013,440 -> ends 27,617,600)
    //   s1        @ 20004160 (inside buckets; written post-binB, buckets dead)
    //   xn        @ 27617600 (6.4MB, own region: binB writes it while buckets live)
    //   hwn aliases xn (xn dead after first k_agg)
    char* ws = (char*)d_ws;
    int*   bcur    = (int*)(ws);
    int*   off     = (int*)(ws + 4096);
    float* dis     = (float*)(ws + 404160);
    int*   srcs    = (int*)(ws + 804160);
    int*   buckets = (int*)(ws + 13604160);
    float* s1      = (float*)(ws + 20004160);
    float* xn      = (float*)(ws + 27617600);
    float* hwn     = xn;  // xn dead after first k_agg

    const int NB_A  = (N_EDGES + TILE - 1) / TILE;      // 782
    const int NB_W  = (N_NODES + 15) / 16;              // 4 nodes/wave, 4 waves/block
    const int NB_G  = (N_NODES + 7) / 8;

    k_zero_bcur<<<1,    512, 0, stream>>>(bcur);
    k_binA     <<<NB_A, 512, 0, stream>>>(src, dst, bcur, buckets);
    k_binB     <<<NBKT, 512, 0, stream>>>(bcur, buckets, x, off, dis, srcs, xn);
    k_agg      <<<NB_W,  256, 0, stream>>>(off, srcs, dis, xn, nullptr, s1);
    k_gemm12   <<<NB_G,  256, 0, stream>>>(s1, W1, b1, W2, dis, hwn);
    k_agg      <<<NB_W,  256, 0, stream>>>(off, srcs, dis, hwn, b2, out);
}